// Round 3
// baseline (82.700 us; speedup 1.0000x reference)
//
#include <hip/hip_runtime.h>

#define BATCH   8
#define HW      (1024 * 1024)
#define NA      512
#define EPSV    1e-8f
#define LAML    0.01f
#define LAMS    0.01f

#define BPB      256                        // blocks per batch
#define NBLOCKS  (BATCH * BPB)              // 2048
#define PIXB     (HW / BPB)                 // 4096 pixels per block
#define NVEC     (PIXB / 4)                 // 1024 float4 per block
#define UNROLL   (NVEC / 256)               // 4 per thread

// Pass 1: per-(batch,chunk,admin) partial sums of score, plain stores (no atomics).
__global__ __launch_bounds__(256) void k_sums(const float* __restrict__ lights,
                                              const float* __restrict__ settle,
                                              const int*   __restrict__ admin,
                                              float*       __restrict__ partial) {
    __shared__ float lsum[4][NA];           // one copy per wave
    const int tid = threadIdx.x;
    const int wid = tid >> 6;

    #pragma unroll
    for (int i = tid; i < 4 * NA; i += 256) ((float*)lsum)[i] = 0.0f;
    __syncthreads();

    const int b     = blockIdx.x >> 8;      // / BPB
    const int chunk = blockIdx.x & (BPB - 1);
    const long base = (long)b * HW + (long)chunk * PIXB;

    const float4* __restrict__ L4 = (const float4*)(lights + base);
    const float4* __restrict__ S4 = (const float4*)(settle + base);
    const int4*   __restrict__ A4 = (const int4*)(admin + base);

    float4 l[UNROLL], s[UNROLL];
    int4   a[UNROLL];
    #pragma unroll
    for (int u = 0; u < UNROLL; ++u) {
        const int v = tid + u * 256;
        l[u] = L4[v];
        s[u] = S4[v];
        a[u] = A4[v];
    }
    __builtin_amdgcn_sched_barrier(0);      // keep all 12 loads in flight
    float* ls = lsum[wid];
    #pragma unroll
    for (int u = 0; u < UNROLL; ++u) {
        atomicAdd(&ls[a[u].x], (l[u].x + LAML) * (s[u].x + LAMS));
        atomicAdd(&ls[a[u].y], (l[u].y + LAML) * (s[u].y + LAMS));
        atomicAdd(&ls[a[u].z], (l[u].z + LAML) * (s[u].z + LAMS));
        atomicAdd(&ls[a[u].w], (l[u].w + LAML) * (s[u].w + LAMS));
    }
    __syncthreads();

    float* dst = partial + (long)blockIdx.x * NA;
    for (int i = tid; i < NA; i += 256)
        dst[i] = lsum[0][i] + lsum[1][i] + lsum[2][i] + lsum[3][i];
}

// Reduce 256 chunk-partials per (batch, admin) and emit factor = C/(S+eps).
__global__ __launch_bounds__(512) void k_reduce(const float* __restrict__ partial,
                                                const float* __restrict__ census,
                                                float*       __restrict__ factor) {
    const int b = blockIdx.x;
    const int a = threadIdx.x;              // 512 threads = NA
    const float* p = partial + (long)b * BPB * NA + a;
    float acc = 0.0f;
    #pragma unroll 8
    for (int c = 0; c < BPB; ++c) acc += p[(long)c * NA];
    factor[b * NA + a] = census[a] / (acc + EPSV);
}

// Pass 2: factor table per batch in LDS, recompute score, write out.
__global__ __launch_bounds__(256) void k_out(const float* __restrict__ lights,
                                             const float* __restrict__ settle,
                                             const int*   __restrict__ admin,
                                             const float* __restrict__ factor,
                                             float*       __restrict__ out) {
    __shared__ float lfac[NA];
    const int tid = threadIdx.x;

    const int b     = blockIdx.x >> 8;
    const int chunk = blockIdx.x & (BPB - 1);

    for (int i = tid; i < NA; i += 256)
        lfac[i] = factor[b * NA + i];
    __syncthreads();

    const long base = (long)b * HW + (long)chunk * PIXB;
    const float4* __restrict__ L4 = (const float4*)(lights + base);
    const float4* __restrict__ S4 = (const float4*)(settle + base);
    const int4*   __restrict__ A4 = (const int4*)(admin + base);
    float4*       __restrict__ O4 = (float4*)(out + base);

    float4 l[UNROLL], s[UNROLL];
    int4   a[UNROLL];
    #pragma unroll
    for (int u = 0; u < UNROLL; ++u) {
        const int v = tid + u * 256;
        l[u] = L4[v];
        s[u] = S4[v];
        a[u] = A4[v];
    }
    __builtin_amdgcn_sched_barrier(0);
    #pragma unroll
    for (int u = 0; u < UNROLL; ++u) {
        float4 o;
        o.x = (l[u].x + LAML) * (s[u].x + LAMS) * lfac[a[u].x];
        o.y = (l[u].y + LAML) * (s[u].y + LAMS) * lfac[a[u].y];
        o.z = (l[u].z + LAML) * (s[u].z + LAMS) * lfac[a[u].z];
        o.w = (l[u].w + LAML) * (s[u].w + LAMS) * lfac[a[u].w];
        O4[tid + u * 256] = o;
    }
}

extern "C" void kernel_launch(void* const* d_in, const int* in_sizes, int n_in,
                              void* d_out, int out_size, void* d_ws, size_t ws_size,
                              hipStream_t stream) {
    const float* lights = (const float*)d_in[0];
    const float* settle = (const float*)d_in[1];
    const int*   admin  = (const int*)d_in[2];
    const float* census = (const float*)d_in[3];
    float*       out    = (float*)d_out;

    // d_out doubles as the 4 MB partial-sum scratch (k_out overwrites it all).
    float* partial = (float*)d_out;
    float* factor  = (float*)d_ws;          // BATCH*NA floats = 16 KB

    k_sums  <<<NBLOCKS, 256, 0, stream>>>(lights, settle, admin, partial);
    k_reduce<<<BATCH,   512, 0, stream>>>(partial, census, factor);
    k_out   <<<NBLOCKS, 256, 0, stream>>>(lights, settle, admin, factor, out);
}

// Round 4
// 82.343 us; speedup vs baseline: 1.0043x; 1.0043x over previous
//
#include <hip/hip_runtime.h>

#define BATCH   8
#define HW      (1024 * 1024)
#define NA      512
#define EPSV    1e-8f
#define LAML    0.01f
#define LAMS    0.01f

#define BPB      256                        // blocks per batch
#define NBLOCKS  (BATCH * BPB)              // 2048
#define PIXB     (HW / BPB)                 // 4096 pixels per block
#define NVEC     (PIXB / 4)                 // 1024 float4 per block
#define UNROLL   (NVEC / 256)               // 4 per thread

// no-return LDS atomic add, workgroup scope, relaxed — should emit ds_add_f32
#define LDS_ADD(slot, val) \
    (void)__hip_atomic_fetch_add(&(slot), (val), __ATOMIC_RELAXED, __HIP_MEMORY_SCOPE_WORKGROUP)

// Pass 1: per-(batch,chunk,admin) partial sums of score, plain stores (no global atomics).
__global__ __launch_bounds__(256) void k_sums(const float* __restrict__ lights,
                                              const float* __restrict__ settle,
                                              const int*   __restrict__ admin,
                                              float*       __restrict__ partial) {
    __shared__ float lsum[4][NA];           // one copy per wave
    const int tid = threadIdx.x;
    const int wid = tid >> 6;

    #pragma unroll
    for (int i = tid; i < 4 * NA; i += 256) ((float*)lsum)[i] = 0.0f;
    __syncthreads();

    const int b     = blockIdx.x >> 8;      // / BPB
    const int chunk = blockIdx.x & (BPB - 1);
    const long base = (long)b * HW + (long)chunk * PIXB;

    const float4* __restrict__ L4 = (const float4*)(lights + base);
    const float4* __restrict__ S4 = (const float4*)(settle + base);
    const int4*   __restrict__ A4 = (const int4*)(admin + base);

    #pragma unroll
    for (int u = 0; u < UNROLL; ++u) {
        const int v = tid + u * 256;
        float4 l = L4[v];
        float4 s = S4[v];
        int4   a = A4[v];
        LDS_ADD(lsum[wid][a.x], (l.x + LAML) * (s.x + LAMS));
        LDS_ADD(lsum[wid][a.y], (l.y + LAML) * (s.y + LAMS));
        LDS_ADD(lsum[wid][a.z], (l.z + LAML) * (s.z + LAMS));
        LDS_ADD(lsum[wid][a.w], (l.w + LAML) * (s.w + LAMS));
    }
    __syncthreads();

    float* dst = partial + (long)blockIdx.x * NA;
    for (int i = tid; i < NA; i += 256)
        dst[i] = lsum[0][i] + lsum[1][i] + lsum[2][i] + lsum[3][i];
}

// Reduce 256 chunk-partials per (batch, admin) and emit factor = C/(S+eps).
__global__ __launch_bounds__(512) void k_reduce(const float* __restrict__ partial,
                                                const float* __restrict__ census,
                                                float*       __restrict__ factor) {
    const int b = blockIdx.x;
    const int a = threadIdx.x;              // 512 threads = NA
    const float* p = partial + (long)b * BPB * NA + a;
    float acc = 0.0f;
    #pragma unroll 8
    for (int c = 0; c < BPB; ++c) acc += p[(long)c * NA];
    factor[b * NA + a] = census[a] / (acc + EPSV);
}

// Pass 2: factor table per batch in LDS, recompute score, write out.
__global__ __launch_bounds__(256) void k_out(const float* __restrict__ lights,
                                             const float* __restrict__ settle,
                                             const int*   __restrict__ admin,
                                             const float* __restrict__ factor,
                                             float*       __restrict__ out) {
    __shared__ float lfac[NA];
    const int tid = threadIdx.x;

    const int b     = blockIdx.x >> 8;
    const int chunk = blockIdx.x & (BPB - 1);

    for (int i = tid; i < NA; i += 256)
        lfac[i] = factor[b * NA + i];
    __syncthreads();

    const long base = (long)b * HW + (long)chunk * PIXB;
    const float4* __restrict__ L4 = (const float4*)(lights + base);
    const float4* __restrict__ S4 = (const float4*)(settle + base);
    const int4*   __restrict__ A4 = (const int4*)(admin + base);
    float4*       __restrict__ O4 = (float4*)(out + base);

    #pragma unroll
    for (int u = 0; u < UNROLL; ++u) {
        const int v = tid + u * 256;
        float4 l = L4[v];
        float4 s = S4[v];
        int4   a = A4[v];
        float4 o;
        o.x = (l.x + LAML) * (s.x + LAMS) * lfac[a.x];
        o.y = (l.y + LAML) * (s.y + LAMS) * lfac[a.y];
        o.z = (l.z + LAML) * (s.z + LAMS) * lfac[a.z];
        o.w = (l.w + LAML) * (s.w + LAMS) * lfac[a.w];
        O4[v] = o;
    }
}

extern "C" void kernel_launch(void* const* d_in, const int* in_sizes, int n_in,
                              void* d_out, int out_size, void* d_ws, size_t ws_size,
                              hipStream_t stream) {
    const float* lights = (const float*)d_in[0];
    const float* settle = (const float*)d_in[1];
    const int*   admin  = (const int*)d_in[2];
    const float* census = (const float*)d_in[3];
    float*       out    = (float*)d_out;

    // d_out doubles as the 4 MB partial-sum scratch (k_out overwrites it all).
    float* partial = (float*)d_out;
    float* factor  = (float*)d_ws;          // BATCH*NA floats = 16 KB

    k_sums  <<<NBLOCKS, 256, 0, stream>>>(lights, settle, admin, partial);
    k_reduce<<<BATCH,   512, 0, stream>>>(partial, census, factor);
    k_out   <<<NBLOCKS, 256, 0, stream>>>(lights, settle, admin, factor, out);
}